// Round 1
// baseline (628.200 us; speedup 1.0000x reference)
//
#include <hip/hip_runtime.h>
#include <hip/hip_bf16.h>

#define NA 8192
#define NB 8192
#define NE 32768
#define NC 8
#define CHW 2048   // 8*16*16

// One block (256 threads) per edge.
// ef = feat_src[src] + feat_dst[dst]  (staged in LDS with zero halo)
// Wh = conv3x3(ef, W) + b             (written to Wh_out)
// m  = u + Wh                         (atomicAdd into h_acc[dst])
__global__ __launch_bounds__(256) void edge_kernel(
    const float* __restrict__ feat_src,   // [Nsrc, 2048]
    const float* __restrict__ feat_dst,   // [Ndst, 2048]
    const float* __restrict__ Wc,         // [8,8,3,3] OIHW
    const float* __restrict__ bias,       // [8]
    const int*   __restrict__ src_idx,    // [E]
    const int*   __restrict__ dst_idx,    // [E]
    float*       __restrict__ Wh_out,     // [E, 2048]
    float*       __restrict__ h_acc,      // [Ndst, 2048] accumulators (pre-zeroed)
    int*         __restrict__ cnt)        // [Ndst] in-degree (pre-zeroed)
{
    __shared__ float s_ef[NC][18][18];    // zero halo -> branch-free conv
    __shared__ float s_u[CHW];
    __shared__ float s_w[NC * NC * 9];

    const int e   = blockIdx.x;
    const int tid = threadIdx.x;
    const int s   = src_idx[e];
    const int d   = dst_idx[e];

    // zero the ef tile (incl. halo) and stage weights
    float* efp = &s_ef[0][0][0];
    for (int i = tid; i < NC * 18 * 18; i += 256) efp[i] = 0.0f;
    for (int i = tid; i < NC * NC * 9; i += 256) s_w[i] = Wc[i];
    __syncthreads();

    // gather u, v (float4-vectorized), write ef interior + keep u
    const float4* up = (const float4*)(feat_src + (size_t)s * CHW);
    const float4* vp = (const float4*)(feat_dst + (size_t)d * CHW);
    #pragma unroll
    for (int k = 0; k < 2; ++k) {
        int i4 = tid + k * 256;            // float4 index 0..511
        float4 u = up[i4];
        float4 v = vp[i4];
        ((float4*)s_u)[i4] = u;
        int base = i4 * 4;
        int c = base >> 8;
        int y = (base >> 4) & 15;
        int x = base & 15;                 // 0,4,8,12 — stays within one row
        s_ef[c][y + 1][x + 1] = u.x + v.x;
        s_ef[c][y + 1][x + 2] = u.y + v.y;
        s_ef[c][y + 1][x + 3] = u.z + v.z;
        s_ef[c][y + 1][x + 4] = u.w + v.w;
    }
    __syncthreads();

    // each thread: one spatial position, all 8 output channels
    const int y = tid >> 4;
    const int x = tid & 15;

    float patch[NC][9];
    #pragma unroll
    for (int ci = 0; ci < NC; ++ci)
        #pragma unroll
        for (int ky = 0; ky < 3; ++ky)
            #pragma unroll
            for (int kx = 0; kx < 3; ++kx)
                patch[ci][ky * 3 + kx] = s_ef[ci][y + ky][x + kx];

    float*       wh = Wh_out + (size_t)e * CHW;
    float*       ha = h_acc  + (size_t)d * CHW;

    #pragma unroll
    for (int co = 0; co < NC; ++co) {
        float acc = bias[co];
        #pragma unroll
        for (int ci = 0; ci < NC; ++ci) {
            #pragma unroll
            for (int t = 0; t < 9; ++t)
                acc = fmaf(patch[ci][t], s_w[(co * NC + ci) * 9 + t], acc);
        }
        const int o = co * 256 + tid;
        wh[o] = acc;
        atomicAdd(&ha[o], s_u[o] + acc);
    }
    if (tid == 0) atomicAdd(&cnt[d], 1);
}

// divide accumulated sums by max(cnt, 1)  (zero in-degree -> 0, since sum==0)
__global__ __launch_bounds__(256) void finalize_kernel(
    float* __restrict__ h, const int* __restrict__ cnt, int n_nodes)
{
    const int Q = CHW / 4;  // float4 per node
    size_t idx = (size_t)blockIdx.x * 256 + threadIdx.x;
    if (idx >= (size_t)n_nodes * Q) return;
    int node = (int)(idx / Q);
    float sc = 1.0f / (float)max(cnt[node], 1);
    float4* p = (float4*)h + idx;
    float4 v = *p;
    v.x *= sc; v.y *= sc; v.z *= sc; v.w *= sc;
    *p = v;
}

extern "C" void kernel_launch(void* const* d_in, const int* in_sizes, int n_in,
                              void* d_out, int out_size, void* d_ws, size_t ws_size,
                              hipStream_t stream) {
    const float* feat_a = (const float*)d_in[0];
    const float* feat_b = (const float*)d_in[1];
    const float* W_e1   = (const float*)d_in[2];
    const float* b_e1   = (const float*)d_in[3];
    const float* W_e2   = (const float*)d_in[4];
    const float* b_e2   = (const float*)d_in[5];
    const int*   src_e1 = (const int*)d_in[6];
    const int*   dst_e1 = (const int*)d_in[7];
    const int*   src_e2 = (const int*)d_in[8];
    const int*   dst_e2 = (const int*)d_in[9];

    float* out = (float*)d_out;
    float* h_a = out;                                  // [NA, 2048]
    float* h_b = out + (size_t)NA * CHW;               // [NB, 2048]
    float* Wh1 = out + (size_t)(NA + NB) * CHW;        // [E, 2048]
    float* Wh2 = Wh1 + (size_t)NE * CHW;               // [E, 2048]

    int* cnt_a = (int*)d_ws;        // [NA]
    int* cnt_b = cnt_a + NA;        // [NB]

    // zero accumulators + counts every call (harness poisons, never restores)
    hipMemsetAsync(h_a, 0, (size_t)(NA + NB) * CHW * sizeof(float), stream);
    hipMemsetAsync(d_ws, 0, (size_t)(NA + NB) * sizeof(int), stream);

    // etype e1: a -> b   (writes Wh1, accumulates into h_b)
    edge_kernel<<<NE, 256, 0, stream>>>(feat_a, feat_b, W_e1, b_e1,
                                        src_e1, dst_e1, Wh1, h_b, cnt_b);
    // etype e2: b -> a   (writes Wh2, accumulates into h_a)
    edge_kernel<<<NE, 256, 0, stream>>>(feat_b, feat_a, W_e2, b_e2,
                                        src_e2, dst_e2, Wh2, h_a, cnt_a);

    const int Q = CHW / 4;
    finalize_kernel<<<(NA * Q + 255) / 256, 256, 0, stream>>>(h_a, cnt_a, NA);
    finalize_kernel<<<(NB * Q + 255) / 256, 256, 0, stream>>>(h_b, cnt_b, NB);
}

// Round 2
// 600.447 us; speedup vs baseline: 1.0462x; 1.0462x over previous
//
#include <hip/hip_runtime.h>
#include <hip/hip_bf16.h>

#define NA 8192
#define NB 8192
#define NE 32768
#define NC 8
#define CHW 2048   // 8*16*16

// Custom zero-fill: h region (float4) + cnt region (int4). The stock
// rocclr fillBuffer kernel measured ~400us for this; grid-stride float4
// fill should be ~30us.
__global__ __launch_bounds__(256) void zero_kernel(
    float4* __restrict__ h, size_t nh4, int4* __restrict__ cnt, size_t nc4)
{
    const float4 z4 = make_float4(0.f, 0.f, 0.f, 0.f);
    const int4 zi4 = make_int4(0, 0, 0, 0);
    size_t stride = (size_t)gridDim.x * blockDim.x;
    for (size_t i = (size_t)blockIdx.x * blockDim.x + threadIdx.x; i < nh4; i += stride)
        h[i] = z4;
    for (size_t i = (size_t)blockIdx.x * blockDim.x + threadIdx.x; i < nc4; i += stride)
        cnt[i] = zi4;
}

// One block (256 threads) per edge.
// ef = feat_src[src] + feat_dst[dst]  (staged in LDS with zero halo)
// Wh = conv3x3(ef, W) + b             (nontemporal store to Wh_out)
// m  = u + Wh                         (atomicAdd into h_acc[dst])
__global__ __launch_bounds__(256) void edge_kernel(
    const float* __restrict__ feat_src,   // [Nsrc, 2048]
    const float* __restrict__ feat_dst,   // [Ndst, 2048]
    const float* __restrict__ Wc,         // [8,8,3,3] OIHW
    const float* __restrict__ bias,       // [8]
    const int*   __restrict__ src_idx,    // [E]
    const int*   __restrict__ dst_idx,    // [E]
    float*       __restrict__ Wh_out,     // [E, 2048]
    float*       __restrict__ h_acc,      // [Ndst, 2048] accumulators (pre-zeroed)
    int*         __restrict__ cnt)        // [Ndst] in-degree (pre-zeroed)
{
    __shared__ float s_ef[NC][18][18];    // zero halo -> branch-free conv
    __shared__ float s_u[CHW];
    __shared__ float s_w[NC * NC * 9];

    const int e   = blockIdx.x;
    const int tid = threadIdx.x;
    const int s   = src_idx[e];
    const int d   = dst_idx[e];

    // zero the ef tile (incl. halo) and stage weights
    float* efp = &s_ef[0][0][0];
    for (int i = tid; i < NC * 18 * 18; i += 256) efp[i] = 0.0f;
    for (int i = tid; i < NC * NC * 9; i += 256) s_w[i] = Wc[i];
    __syncthreads();

    // gather u, v (float4-vectorized), write ef interior + keep u
    const float4* up = (const float4*)(feat_src + (size_t)s * CHW);
    const float4* vp = (const float4*)(feat_dst + (size_t)d * CHW);
    #pragma unroll
    for (int k = 0; k < 2; ++k) {
        int i4 = tid + k * 256;            // float4 index 0..511
        float4 u = up[i4];
        float4 v = vp[i4];
        ((float4*)s_u)[i4] = u;
        int base = i4 * 4;
        int c = base >> 8;
        int y = (base >> 4) & 15;
        int x = base & 15;                 // 0,4,8,12 — stays within one row
        s_ef[c][y + 1][x + 1] = u.x + v.x;
        s_ef[c][y + 1][x + 2] = u.y + v.y;
        s_ef[c][y + 1][x + 3] = u.z + v.z;
        s_ef[c][y + 1][x + 4] = u.w + v.w;
    }
    __syncthreads();

    // each thread: one spatial position, all 8 output channels
    const int y = tid >> 4;
    const int x = tid & 15;

    float patch[NC][9];
    #pragma unroll
    for (int ci = 0; ci < NC; ++ci)
        #pragma unroll
        for (int ky = 0; ky < 3; ++ky)
            #pragma unroll
            for (int kx = 0; kx < 3; ++kx)
                patch[ci][ky * 3 + kx] = s_ef[ci][y + ky][x + kx];

    float*       wh = Wh_out + (size_t)e * CHW;
    float*       ha = h_acc  + (size_t)d * CHW;

    #pragma unroll
    for (int co = 0; co < NC; ++co) {
        float acc = bias[co];
        #pragma unroll
        for (int ci = 0; ci < NC; ++ci) {
            #pragma unroll
            for (int t = 0; t < 9; ++t)
                acc = fmaf(patch[ci][t], s_w[(co * NC + ci) * 9 + t], acc);
        }
        const int o = co * 256 + tid;
        __builtin_nontemporal_store(acc, &wh[o]);   // Wh is streamed, keep L3 for feats
        atomicAdd(&ha[o], s_u[o] + acc);
    }
    if (tid == 0) atomicAdd(&cnt[d], 1);
}

// divide accumulated sums by max(cnt, 1)  (zero in-degree -> 0, since sum==0)
__global__ __launch_bounds__(256) void finalize_kernel(
    float* __restrict__ h, const int* __restrict__ cnt, int n_nodes)
{
    const int Q = CHW / 4;  // float4 per node
    size_t idx = (size_t)blockIdx.x * 256 + threadIdx.x;
    if (idx >= (size_t)n_nodes * Q) return;
    int node = (int)(idx / Q);
    float sc = 1.0f / (float)max(cnt[node], 1);
    float4* p = (float4*)h + idx;
    float4 v = *p;
    v.x *= sc; v.y *= sc; v.z *= sc; v.w *= sc;
    *p = v;
}

extern "C" void kernel_launch(void* const* d_in, const int* in_sizes, int n_in,
                              void* d_out, int out_size, void* d_ws, size_t ws_size,
                              hipStream_t stream) {
    const float* feat_a = (const float*)d_in[0];
    const float* feat_b = (const float*)d_in[1];
    const float* W_e1   = (const float*)d_in[2];
    const float* b_e1   = (const float*)d_in[3];
    const float* W_e2   = (const float*)d_in[4];
    const float* b_e2   = (const float*)d_in[5];
    const int*   src_e1 = (const int*)d_in[6];
    const int*   dst_e1 = (const int*)d_in[7];
    const int*   src_e2 = (const int*)d_in[8];
    const int*   dst_e2 = (const int*)d_in[9];

    float* out = (float*)d_out;
    float* h_a = out;                                  // [NA, 2048]
    float* h_b = out + (size_t)NA * CHW;               // [NB, 2048]
    float* Wh1 = out + (size_t)(NA + NB) * CHW;        // [E, 2048]
    float* Wh2 = Wh1 + (size_t)NE * CHW;               // [E, 2048]

    int* cnt_a = (int*)d_ws;        // [NA]
    int* cnt_b = cnt_a + NA;        // [NB]

    // zero accumulators + counts every call (custom fill; stock memset was ~400us)
    size_t nh4 = (size_t)(NA + NB) * CHW / 4;
    size_t nc4 = (size_t)(NA + NB) / 4;
    zero_kernel<<<2048, 256, 0, stream>>>((float4*)h_a, nh4, (int4*)d_ws, nc4);

    // etype e1: a -> b   (writes Wh1, accumulates into h_b)
    edge_kernel<<<NE, 256, 0, stream>>>(feat_a, feat_b, W_e1, b_e1,
                                        src_e1, dst_e1, Wh1, h_b, cnt_b);
    // etype e2: b -> a   (writes Wh2, accumulates into h_a)
    edge_kernel<<<NE, 256, 0, stream>>>(feat_b, feat_a, W_e2, b_e2,
                                        src_e2, dst_e2, Wh2, h_a, cnt_a);

    const int Q = CHW / 4;
    finalize_kernel<<<(NA * Q + 255) / 256, 256, 0, stream>>>(h_a, cnt_a, NA);
    finalize_kernel<<<(NB * Q + 255) / 256, 256, 0, stream>>>(h_b, cnt_b, NB);
}